// Round 10
// baseline (482.980 us; speedup 1.0000x reference)
//
#include <hip/hip_runtime.h>
#include <math.h>

#define BV 2
#define TV 16
#define NV 2000
#define FIN 16
#define EV 32000
#define ETV 34000
#define GV 32
#define DD 64
#define FFV 2048

// workspace layout (float offsets)
#define OFF_H     0L          // h fp32 [32*2000*128]
#define OFF_ASRC  8192000L
#define OFF_ADST  8448000L
#define OFF_Y     8704000L    // outg [2*2000*16*32]
#define OFF_WF    10752000L   // fused Wf [32*192], bfv [192]
#define OFF_Z1    12800000L
#define OFF_SCAL  13056000L   // scal[16], cnt[2000], den[256000] (one memset), then rowptr/csr
#define OFF_WT    14500000L   // wt [32*34000*4] = 4352000 floats
#define OFF_PACK  19000000L   // pw1 [131072 bf16], pw2 [131072 bf16]
#define OFF_TBL   19400000L   // int tbl[544]

typedef __attribute__((ext_vector_type(8))) short bf16x8;
typedef __attribute__((ext_vector_type(4))) float f32x4;

__device__ __forceinline__ short f2bf(float f) {
    union { float f; unsigned u; } v; v.f = f;
    unsigned r = v.u + 0x7FFFu + ((v.u >> 16) & 1u);   // round-to-nearest-even
    return (short)(r >> 16);
}

// ---------------- K_A: edge-weight sum (atomic) + in-degree histogram ----------------
__global__ void ew_hist_kernel(const int* __restrict__ edge_index, const float* __restrict__ ew,
                               int* __restrict__ deg, float* __restrict__ scal) {
    int e = blockIdx.x * 256 + threadIdx.x;
    float v = (e < EV) ? ew[e] : 0.f;
#pragma unroll
    for (int d = 32; d; d >>= 1) v += __shfl_xor(v, d);
    if ((threadIdx.x & 63) == 0) atomicAdd(&scal[0], v);
    if (e < ETV) {
        int dst = (e < EV) ? edge_index[EV + e] : (e - EV);
        atomicAdd(&deg[dst], 1);
    }
}

// ---------------- K_B: exclusive scan -> rowptr, copy -> cnt ----------------
__global__ void scan_kernel(const int* __restrict__ deg, int* __restrict__ rowptr, int* __restrict__ cnt) {
    __shared__ int tot[256];
    int tid = threadIdx.x;
    int base = tid * 8;
    int local[8]; int s = 0;
    for (int i = 0; i < 8; i++) { int v = (base + i < NV) ? deg[base + i] : 0; local[i] = s; s += v; }
    tot[tid] = s; __syncthreads();
    for (int d = 1; d < 256; d <<= 1) {
        int v = (tid >= d) ? tot[tid - d] : 0;
        __syncthreads();
        tot[tid] += v;
        __syncthreads();
    }
    int ex = tot[tid] - s;
    for (int i = 0; i < 8; i++) {
        int idx = base + i;
        if (idx < NV) { int rp = ex + local[i]; rowptr[idx] = rp; cnt[idx] = rp; }
    }
    if (tid == 255) rowptr[NV] = tot[255];
}

// ---------------- K_C: fuse (blocks 0-23) + prep2 (block 24) + MFMA probe (block 25) ----------------
__global__ void prep_fuse_probe_kernel(const float* __restrict__ Wproj, const float* __restrict__ bproj,
                                       const float* __restrict__ Wqkv, const float* __restrict__ bqkv,
                                       float* __restrict__ Wf, float* __restrict__ bfv,
                                       const float* __restrict__ W_edge, const float* __restrict__ att_edge,
                                       float* __restrict__ scal, int* __restrict__ tbl) {
    int bid = blockIdx.x, tid = threadIdx.x;
    if (bid < 24) {
        int i = bid * 256 + tid;
        if (i < 32 * 192) {
            int c = i / 192, j = i - c * 192;
            float s = 0.f;
#pragma unroll
            for (int d = 0; d < 64; d++) s += Wproj[c * 64 + d] * Wqkv[d * 192 + j];
            Wf[i] = s;
        }
        if (i < 192) {
            float s = bqkv[i];
#pragma unroll
            for (int d = 0; d < 64; d++) s += bproj[d] * Wqkv[d * 192 + i];
            bfv[i] = s;
        }
    } else if (bid == 24) {
        __shared__ float red[128];
        if (tid < 128) red[tid] = W_edge[tid] * att_edge[tid];
        __syncthreads();
        if (tid == 0) scal[0] = scal[0] * (1.f / (float)EV);
        if (tid < 4) {
            float t = 0.f;
#pragma unroll
            for (int c = 0; c < 32; c++) t += red[tid * 32 + c];
            scal[1 + tid] = t;
        }
    } else {
        if (tid < 64) {
            int lane = tid;
            int quad = lane >> 4, L = lane & 15;
            short one = f2bf(1.0f), Ls = f2bf((float)L);
            bf16x8 ones, lv, alab;
#pragma unroll
            for (int j = 0; j < 8; j++) { ones[j] = one; lv[j] = Ls; alab[j] = f2bf((float)(quad * 8 + j)); }
            f32x4 zero = {0.f, 0.f, 0.f, 0.f};
            f32x4 dm = __builtin_amdgcn_mfma_f32_16x16x32_bf16(lv, ones, zero, 0, 0, 0);
            f32x4 dn = __builtin_amdgcn_mfma_f32_16x16x32_bf16(ones, lv, zero, 0, 0, 0);
#pragma unroll
            for (int r = 0; r < 4; r++) {
                tbl[lane * 4 + r]       = (int)(dm[r] * (1.f / 32.f) + 0.5f);
                tbl[256 + lane * 4 + r] = (int)(dn[r] * (1.f / 32.f) + 0.5f);
            }
            for (int b = 0; b < 32; b++) {
                bf16x8 bh;
#pragma unroll
                for (int j = 0; j < 8; j++) bh[j] = (quad == (b >> 3) && j == (b & 7)) ? one : (short)0;
                f32x4 d = __builtin_amdgcn_mfma_f32_16x16x32_bf16(alab, bh, zero, 0, 0, 0);
                int a = (int)(d[0] + 0.5f);
                if (lane == 0) tbl[512 + a] = b;
            }
        }
    }
}

// ---------------- K_pack: W1 + W2 -> bf16 fragment order ----------------
__global__ void pack_w_kernel(const float* __restrict__ W1, const float* __restrict__ W2,
                              short* __restrict__ pw1, short* __restrict__ pw2,
                              const int* __restrict__ tbl) {
    int idx = blockIdx.x * 256 + threadIdx.x;   // 0..262143
    if (idx < 131072) {
        int i = idx;
        int k = i >> 11, n = i & 2047;
        int s = k >> 5, kp = k & 31;
        int b = tbl[512 + kp];
        int lane = (b >> 3) * 16 + (n & 15), jj = b & 7;
        int t = n >> 4;
        pw1[(((t * 2 + s) * 64 + lane) << 3) + jj] = f2bf(W1[i]);
    } else {
        int i = idx - 131072;
        int k = i >> 6, n = i & 63;
        int kt = k >> 5, kp = k & 31;
        int b = tbl[512 + kp];
        int lane = (b >> 3) * 16 + (n & 15), jj = b & 7;
        int nt = n >> 4;
        pw2[(((kt * 4 + nt) * 64 + lane) << 3) + jj] = f2bf(W2[i]);
    }
}

// ---------------- K_D: scatter edges into CSR (now also records dst) ----------------
__global__ void scatter_kernel(const int* __restrict__ edge_index, const float* __restrict__ edge_weight,
                               const float* __restrict__ scal, int* __restrict__ cnt,
                               int* __restrict__ csr_src, int* __restrict__ csr_dst,
                               float* __restrict__ csr_ew) {
    int e = blockIdx.x * 256 + threadIdx.x;
    if (e >= ETV) return;
    int src, dst; float w;
    if (e < EV) { src = edge_index[e]; dst = edge_index[EV + e]; w = edge_weight[e]; }
    else        { src = dst = e - EV; w = scal[0]; }
    int pos = atomicAdd(&cnt[dst], 1);
    csr_src[pos] = src; csr_dst[pos] = dst; csr_ew[pos] = w;
}

// ---------------- K4: h = x@W_gat (fp32), a_src, a_dst (4 rows/wave, weights in regs) ----------------
__global__ __launch_bounds__(256) void gat_h_kernel(const float* __restrict__ x, const float* __restrict__ W_gat,
                                                    const float* __restrict__ att_src, const float* __restrict__ att_dst,
                                                    float* __restrict__ h, float* __restrict__ a_src,
                                                    float* __restrict__ a_dst) {
    int tid = threadIdx.x;
    int lane = tid & 63, wave = tid >> 6;
    int row0 = blockIdx.x * 16 + wave * 4;
    float w0[16], w1[16];
#pragma unroll
    for (int f = 0; f < 16; f++) { w0[f] = W_gat[f * 128 + lane]; w1[f] = W_gat[f * 128 + 64 + lane]; }
    float as0 = att_src[lane], as1 = att_src[lane + 64];
    float ad0 = att_dst[lane], ad1 = att_dst[lane + 64];
#pragma unroll
    for (int r = 0; r < 4; r++) {
        int row = row0 + r;
        const float4* xr = (const float4*)(x + (long)row * 16);
        float4 xa = xr[0], xb = xr[1], xc = xr[2], xd = xr[3];
        float xv[16] = {xa.x, xa.y, xa.z, xa.w, xb.x, xb.y, xb.z, xb.w,
                        xc.x, xc.y, xc.z, xc.w, xd.x, xd.y, xd.z, xd.w};
        float h0 = 0.f, h1 = 0.f;
#pragma unroll
        for (int f = 0; f < 16; f++) { h0 += xv[f] * w0[f]; h1 += xv[f] * w1[f]; }
        h[(long)row * 128 + lane] = h0;
        h[(long)row * 128 + 64 + lane] = h1;
        float p0 = h0 * as0, p1 = h1 * as1;
        float q0 = h0 * ad0, q1 = h1 * ad1;
#pragma unroll
        for (int d = 1; d < 32; d <<= 1) {
            p0 += __shfl_xor(p0, d); p1 += __shfl_xor(p1, d);
            q0 += __shfl_xor(q0, d); q1 += __shfl_xor(q1, d);
        }
        if (lane == 0)  { a_src[row * 4 + 0] = p0; a_src[row * 4 + 2] = p1; a_dst[row * 4 + 0] = q0; a_dst[row * 4 + 2] = q1; }
        if (lane == 32) { a_src[row * 4 + 1] = p0; a_src[row * 4 + 3] = p1; a_dst[row * 4 + 1] = q0; a_dst[row * 4 + 3] = q1; }
    }
}

// ---------------- K_wt: per-(g,edge) softmax weights + atomic denominators ----------------
__global__ void wt_kernel(const int* __restrict__ csr_src, const int* __restrict__ csr_dst,
                          const float* __restrict__ csr_ew, const float* __restrict__ a_src,
                          const float* __restrict__ a_dst, const float* __restrict__ scal,
                          float* __restrict__ wtbuf, float* __restrict__ den) {
    long id = (long)blockIdx.x * 256 + threadIdx.x;   // over GV*ETV
    if (id >= (long)GV * ETV) return;
    int g = (int)(id / ETV);
    int e = (int)(id - (long)g * ETV);
    int se = csr_src[e], de = csr_dst[e];
    float ew = csr_ew[e];
    float s0 = scal[1], s1 = scal[2], s2 = scal[3], s3 = scal[4];
    float4 as = *(const float4*)(a_src + ((long)g * NV + se) * 4);
    float4 ad = *(const float4*)(a_dst + ((long)g * NV + de) * 4);
    float l0 = as.x + ad.x + ew * s0; l0 = l0 > 0.f ? l0 : 0.2f * l0; float e0 = __expf(l0);
    float l1 = as.y + ad.y + ew * s1; l1 = l1 > 0.f ? l1 : 0.2f * l1; float e1 = __expf(l1);
    float l2 = as.z + ad.z + ew * s2; l2 = l2 > 0.f ? l2 : 0.2f * l2; float e2 = __expf(l2);
    float l3 = as.w + ad.w + ew * s3; l3 = l3 > 0.f ? l3 : 0.2f * l3; float e3 = __expf(l3);
    float4 o = {e0, e1, e2, e3};
    *(float4*)(wtbuf + id * 4) = o;
    float* dp = den + ((long)g * NV + de) * 4;
    atomicAdd(dp + 0, e0); atomicAdd(dp + 1, e1);
    atomicAdd(dp + 2, e2); atomicAdd(dp + 3, e3);
}

// ---------------- K5: pure weighted gather + head mean -> outg ----------------
// 16000 blocks, XCD-swizzled; one wave per (g,n). half=lane>>5 edge parity, c=lane&31 (4 ch).
__global__ __launch_bounds__(256) void gat_agg_kernel(const float* __restrict__ h,
                                                      const int* __restrict__ rowptr,
                                                      const int* __restrict__ csr_src,
                                                      const float* __restrict__ wtbuf,
                                                      const float* __restrict__ den,
                                                      const float* __restrict__ gat_bias,
                                                      float* __restrict__ outg) {
    __shared__ int   ssrc[4][64];
    __shared__ float swt[4][64][4];   // slot-major: conflict-free reads
    int tid = threadIdx.x;
    int lane = tid & 63, wave = tid >> 6;
    int bid = blockIdx.x;
    int xcd = bid & 7, j = bid >> 3;
    int g = xcd * 4 + j / 500;
    int n = (j % 500) * 4 + wave;
    const float* hg = h + (long)g * NV * 128;
    const float* wtg = wtbuf + (long)g * ETV * 4;
    int start = rowptr[n], end = rowptr[n + 1];
    int half = lane >> 5, c = lane & 31;
    int hsel = c >> 3;
    float4 dv = *(const float4*)(den + ((long)g * NV + n) * 4);
    float denh = (hsel == 0) ? dv.x : (hsel == 1) ? dv.y : (hsel == 2) ? dv.z : dv.w;
    float inv = 1.f / (denh + 1e-16f);
    float4 msg = {0.f, 0.f, 0.f, 0.f};
    for (int base = start; base < end; base += 64) {
        int idx = base + lane;
        int se = 0; float4 w4 = {0.f, 0.f, 0.f, 0.f};
        if (idx < end) {
            se = csr_src[idx];
            w4 = *(const float4*)(wtg + (long)idx * 4);
        }
        ssrc[wave][lane] = se;
        *(float4*)&swt[wave][lane][0] = w4;
        __builtin_amdgcn_wave_barrier();
        int cn = end - base; if (cn > 64) cn = 64;
        int npairs = (cn + 1) >> 1;
#pragma unroll 4
        for (int i = 0; i < npairs; i++) {
            int slot = 2 * i + half;
            int sse = ssrc[wave][slot];
            float wt = swt[wave][slot][hsel];          // staged 0 for slots >= cn
            const float4 hv = *(const float4*)(hg + (long)sse * 128 + c * 4);
            msg.x += wt * hv.x; msg.y += wt * hv.y; msg.z += wt * hv.z; msg.w += wt * hv.w;
        }
        __builtin_amdgcn_wave_barrier();
    }
    msg.x *= inv; msg.y *= inv; msg.z *= inv; msg.w *= inv;
    // combine edge halves, then head mean (c bits 3,4)
    msg.x += __shfl_xor(msg.x, 32); msg.y += __shfl_xor(msg.y, 32);
    msg.z += __shfl_xor(msg.z, 32); msg.w += __shfl_xor(msg.w, 32);
    msg.x += __shfl_xor(msg.x, 8);  msg.y += __shfl_xor(msg.y, 8);
    msg.z += __shfl_xor(msg.z, 8);  msg.w += __shfl_xor(msg.w, 8);
    msg.x += __shfl_xor(msg.x, 16); msg.y += __shfl_xor(msg.y, 16);
    msg.z += __shfl_xor(msg.z, 16); msg.w += __shfl_xor(msg.w, 16);
    if (half == 0 && c < 8) {
        const float4 gb = *(const float4*)(gat_bias + c * 4);
        float4 o;
        o.x = 0.25f * msg.x + gb.x; o.y = 0.25f * msg.y + gb.y;
        o.z = 0.25f * msg.z + gb.z; o.w = 0.25f * msg.w + gb.w;
        int b = g / TV, tt = g - b * TV;
        *(float4*)(outg + (((long)(b * NV + n)) * TV + tt) * 32 + c * 4) = o;
    }
}

// ---------------- K6: fused qkv (K=32) + attention + Wo + LN1 -> z1 ----------------
__global__ __launch_bounds__(256) void attn_kernel(const float* __restrict__ og, const float* __restrict__ Wf,
                                                   const float* __restrict__ bfv, const float* __restrict__ Wproj,
                                                   const float* __restrict__ bproj, const float* __restrict__ Wo,
                                                   const float* __restrict__ bo, const float* __restrict__ ln1g,
                                                   const float* __restrict__ ln1b, float* __restrict__ z1) {
    __shared__ float ot[512], wkvf[4096], kb[1024], vb[1024], qv[64], pv[64], sc[64], yv[64];
    int tid = threadIdx.x;
    int bn = blockIdx.x;
    const float* ob = og + (long)bn * 512;
    for (int i = tid; i < 512; i += 256) ot[i] = ob[i];
    for (int i = tid; i < 4096; i += 256) { int d = i >> 7, j = i & 127; wkvf[i] = Wf[d * 192 + 64 + j]; }
    __syncthreads();
    {
        int j = tid & 127, tb = tid >> 7;
        float wcol[32];
#pragma unroll
        for (int d = 0; d < 32; d++) wcol[d] = wkvf[d * 128 + j];
        float bias = bfv[64 + j];
#pragma unroll
        for (int k = 0; k < 8; k++) {
            int t = 2 * k + tb;
            const float* orow = &ot[t * 32];
            float a = bias;
#pragma unroll
            for (int d = 0; d < 32; d++) a += orow[d] * wcol[d];
            if (j < 64) kb[t * 64 + j] = a; else vb[t * 64 + (j - 64)] = a;
        }
    }
    if (tid < 64) {
        float a = bfv[tid];
        float yr = bproj[tid];
#pragma unroll
        for (int d = 0; d < 32; d++) {
            float od = ot[15 * 32 + d];
            a  += od * Wf[d * 192 + tid];
            yr += od * Wproj[d * 64 + tid];
        }
        qv[tid] = a; yv[tid] = yr;
    }
    __syncthreads();
    if (tid < 64) {
        int hh = tid >> 4, t = tid & 15;
        float s = 0.f;
#pragma unroll
        for (int dd = 0; dd < 16; dd++) s += qv[hh * 16 + dd] * kb[t * 64 + hh * 16 + dd];
        sc[tid] = s * 0.25f;
    }
    __syncthreads();
    if (tid < 64) {
        int hh = tid >> 4;
        float m = -INFINITY;
        for (int t = 0; t < 16; t++) m = fmaxf(m, sc[hh * 16 + t]);
        float den = 0.f;
        for (int t = 0; t < 16; t++) den += __expf(sc[hh * 16 + t] - m);
        pv[tid] = __expf(sc[tid] - m) / den;
    }
    __syncthreads();
    if (tid < 64) {
        int hh = tid >> 4;
        float ctx = 0.f;
#pragma unroll
        for (int t = 0; t < 16; t++) ctx += pv[hh * 16 + t] * vb[t * 64 + tid];
        sc[tid] = ctx;
    }
    __syncthreads();
    if (tid < 64) {
        float o = bo[tid];
#pragma unroll
        for (int j = 0; j < 64; j++) o += sc[j] * Wo[j * 64 + tid];
        float r = yv[tid] + o;
        float sum = r, sq = r * r;
#pragma unroll
        for (int d = 32; d; d >>= 1) { sum += __shfl_xor(sum, d); sq += __shfl_xor(sq, d); }
        float mu = sum * (1.f / 64.f);
        float var = sq * (1.f / 64.f) - mu * mu;
        float zz = (r - mu) * rsqrtf(var + 1e-5f) * ln1g[tid] + ln1b[tid];
        z1[(long)bn * 64 + tid] = zz;
    }
}

// ---------------- K7: FF via bf16 MFMA (layout-table-driven) + residual + LN2 -> out ----------------
__global__ __launch_bounds__(256) void ff_mfma_kernel(const float* __restrict__ z1,
        const short* __restrict__ pw1, const short* __restrict__ pw2,
        const float* __restrict__ b1, const float* __restrict__ b2,
        const float* __restrict__ ln2g, const float* __restrict__ ln2b,
        const int* __restrict__ tbl, float* __restrict__ out) {
    __shared__ __align__(16) short zb[16 * 72];
    __shared__ __align__(16) short hb[4][16 * 520];
    __shared__ float part[4 * 16 * 64];
    int tid = threadIdx.x;
    int row0 = blockIdx.x * 16;
    for (int i = tid; i < 1024; i += 256)
        zb[(i >> 6) * 72 + (i & 63)] = f2bf(z1[(long)row0 * 64 + i]);
    __syncthreads();
    int lane = tid & 63, wv = tid >> 6;
    int quad = lane >> 4, m16 = lane & 15;
    int mo[4], no[4];
#pragma unroll
    for (int r = 0; r < 4; r++) { mo[r] = tbl[lane * 4 + r]; no[r] = tbl[256 + lane * 4 + r]; }
    bf16x8 a0 = *(const bf16x8*)&zb[m16 * 72 + quad * 8];
    bf16x8 a1 = *(const bf16x8*)&zb[m16 * 72 + 32 + quad * 8];
    const short* pb1 = pw1 + (size_t)wv * 32 * 2 * 512;
    short* hbw = &hb[wv][0];
#pragma unroll 4
    for (int t = 0; t < 32; t++) {
        bf16x8 bA = *(const bf16x8*)(pb1 + ((t * 2 + 0) << 9) + (lane << 3));
        bf16x8 bB = *(const bf16x8*)(pb1 + ((t * 2 + 1) << 9) + (lane << 3));
        f32x4 acc = {0.f, 0.f, 0.f, 0.f};
        acc = __builtin_amdgcn_mfma_f32_16x16x32_bf16(a0, bA, acc, 0, 0, 0);
        acc = __builtin_amdgcn_mfma_f32_16x16x32_bf16(a1, bB, acc, 0, 0, 0);
#pragma unroll
        for (int r = 0; r < 4; r++) {
            float v = acc[r] + b1[wv * 512 + t * 16 + no[r]];
            v = v > 0.f ? v : 0.f;
            hbw[mo[r] * 520 + t * 16 + no[r]] = f2bf(v);
        }
    }
    __syncthreads();
    f32x4 acc2[4] = {{0.f,0.f,0.f,0.f},{0.f,0.f,0.f,0.f},{0.f,0.f,0.f,0.f},{0.f,0.f,0.f,0.f}};
    const short* pb2 = pw2 + (size_t)wv * 16 * 4 * 512;
#pragma unroll 2
    for (int kt = 0; kt < 16; kt++) {
        bf16x8 af = *(const bf16x8*)&hbw[m16 * 520 + kt * 32 + quad * 8];
#pragma unroll
        for (int nt = 0; nt < 4; nt++) {
            bf16x8 bfr = *(const bf16x8*)(pb2 + ((kt * 4 + nt) << 9) + (lane << 3));
            acc2[nt] = __builtin_amdgcn_mfma_f32_16x16x32_bf16(af, bfr, acc2[nt], 0, 0, 0);
        }
    }
#pragma unroll
    for (int nt = 0; nt < 4; nt++)
#pragma unroll
        for (int r = 0; r < 4; r++)
            part[wv * 1024 + mo[r] * 64 + nt * 16 + no[r]] = acc2[nt][r];
    __syncthreads();
    int col = tid & 63, rq = tid >> 6;
    float g = ln2g[col], bb = ln2b[col], bias2 = b2[col];
#pragma unroll
    for (int k2 = 0; k2 < 4; k2++) {
        int r = rq + k2 * 4;
        float val = part[r * 64 + col] + part[1024 + r * 64 + col]
                  + part[2048 + r * 64 + col] + part[3072 + r * 64 + col]
                  + z1[(long)(row0 + r) * 64 + col] + bias2;
        float sum = val, sq = val * val;
#pragma unroll
        for (int dlt = 32; dlt; dlt >>= 1) { sum += __shfl_xor(sum, dlt); sq += __shfl_xor(sq, dlt); }
        float mu = sum * (1.f / 64.f);
        float var = sq * (1.f / 64.f) - mu * mu;
        out[(long)(row0 + r) * 64 + col] = (val - mu) * rsqrtf(var + 1e-5f) * g + bb;
    }
}

extern "C" void kernel_launch(void* const* d_in, const int* in_sizes, int n_in,
                              void* d_out, int out_size, void* d_ws, size_t ws_size,
                              hipStream_t stream) {
    const float* x_seq      = (const float*)d_in[0];
    const int*   edge_index = (const int*)  d_in[1];
    const float* edge_weight= (const float*)d_in[2];
    const float* W_gat      = (const float*)d_in[3];
    const float* att_src    = (const float*)d_in[4];
    const float* att_dst    = (const float*)d_in[5];
    const float* W_edge     = (const float*)d_in[6];
    const float* att_edge   = (const float*)d_in[7];
    const float* gat_bias   = (const float*)d_in[8];
    const float* W_proj     = (const float*)d_in[9];
    const float* b_proj     = (const float*)d_in[10];
    const float* Wqkv       = (const float*)d_in[11];
    const float* bqkv       = (const float*)d_in[12];
    const float* Wo         = (const float*)d_in[13];
    const float* bo         = (const float*)d_in[14];
    const float* ln1g       = (const float*)d_in[15];
    const float* ln1b       = (const float*)d_in[16];
    const float* W1         = (const float*)d_in[17];
    const float* b1         = (const float*)d_in[18];
    const float* W2         = (const float*)d_in[19];
    const float* b2         = (const float*)d_in[20];
    const float* ln2g       = (const float*)d_in[21];
    const float* ln2b       = (const float*)d_in[22];
    float* outp = (float*)d_out;

    float* wsf = (float*)d_ws;
    float* h      = wsf + OFF_H;
    float* a_src  = wsf + OFF_ASRC;
    float* a_dst  = wsf + OFF_ADST;
    float* outg   = wsf + OFF_Y;
    float* Wfused = wsf + OFF_WF;
    float* bfv    = Wfused + 32 * 192;
    float* z1     = wsf + OFF_Z1;
    float* scal   = wsf + OFF_SCAL;
    int*   cnt    = (int*)(wsf + OFF_SCAL + 16);
    float* den    = wsf + OFF_SCAL + 16 + 2000;        // [32*2000*4] zeroed by memset
    int*   rowptr = (int*)(den + 256000);
    int*   csr_src= rowptr + 2001;
    int*   csr_dst= csr_src + 34000;
    float* csr_ew = (float*)(csr_dst + 34000);
    float* wtbuf  = wsf + OFF_WT;
    short* pw1    = (short*)(wsf + OFF_PACK);
    short* pw2    = pw1 + 131072;
    int*   tbl    = (int*)(wsf + OFF_TBL);

    // one memset covers scal[16] + cnt[2000] + den[256000]
    hipMemsetAsync(scal, 0, (16 + 2000 + 256000) * sizeof(float), stream);
    ew_hist_kernel<<<(ETV + 255) / 256, 256, 0, stream>>>(edge_index, edge_weight, cnt, scal);
    scan_kernel<<<1, 256, 0, stream>>>(cnt, rowptr, cnt);
    prep_fuse_probe_kernel<<<26, 256, 0, stream>>>(W_proj, b_proj, Wqkv, bqkv, Wfused, bfv,
                                                   W_edge, att_edge, scal, tbl);
    pack_w_kernel<<<1024, 256, 0, stream>>>(W1, W2, pw1, pw2, tbl);
    scatter_kernel<<<(ETV + 255) / 256, 256, 0, stream>>>(edge_index, edge_weight, scal, cnt,
                                                          csr_src, csr_dst, csr_ew);
    gat_h_kernel<<<GV * NV / 16, 256, 0, stream>>>(x_seq, W_gat, att_src, att_dst, h, a_src, a_dst);
    wt_kernel<<<(GV * ETV + 255) / 256, 256, 0, stream>>>(csr_src, csr_dst, csr_ew, a_src, a_dst,
                                                          scal, wtbuf, den);
    gat_agg_kernel<<<GV * NV / 4, 256, 0, stream>>>(h, rowptr, csr_src, wtbuf, den, gat_bias, outg);
    attn_kernel<<<BV * NV, 256, 0, stream>>>(outg, Wfused, bfv, W_proj, b_proj, Wo, bo, ln1g, ln1b, z1);
    ff_mfma_kernel<<<BV * NV / 16, 256, 0, stream>>>(z1, pw1, pw2, b1, b2, ln2g, ln2b, tbl, outp);
}

// Round 11
// 218.695 us; speedup vs baseline: 2.2085x; 2.2085x over previous
//
#include <hip/hip_runtime.h>
#include <math.h>

#define BV 2
#define TV 16
#define NV 2000
#define FIN 16
#define EV 32000
#define ETV 34000
#define GV 32
#define DD 64
#define FFV 2048

// workspace layout (float offsets)
#define OFF_H     0L          // h fp32 [32*2000*128]
#define OFF_ASRC  8192000L
#define OFF_ADST  8448000L
#define OFF_Y     8704000L    // outg [2*2000*16*32]
#define OFF_WF    10752000L   // fused Wf [32*192], bfv [192]
#define OFF_Z1    12800000L
#define OFF_SCAL  13056000L   // scal[16], cnt[2000], rowptr[2001], csr_src[34000], csr_ew[34000]
#define OFF_PACK  19000000L   // pw1 [131072 bf16], pw2 [131072 bf16]
#define OFF_TBL   19400000L   // int tbl[544]

// node-A block ranges
#define GH_BLOCKS 4000        // gat_h
#define EH_BLOCKS 133         // ew-sum + hist
#define FU_BLOCKS 24          // fuse

typedef __attribute__((ext_vector_type(8))) short bf16x8;
typedef __attribute__((ext_vector_type(4))) float f32x4;

__device__ __forceinline__ short f2bf(float f) {
    union { float f; unsigned u; } v; v.f = f;
    unsigned r = v.u + 0x7FFFu + ((v.u >> 16) & 1u);   // round-to-nearest-even
    return (short)(r >> 16);
}

// ---------------- Node A: gat_h | ew-sum+hist | fuse | head-scalars | MFMA probe ----------------
__global__ __launch_bounds__(256) void mega_kernel(const float* __restrict__ x, const float* __restrict__ W_gat,
        const float* __restrict__ att_src, const float* __restrict__ att_dst,
        float* __restrict__ h, float* __restrict__ a_src, float* __restrict__ a_dst,
        const int* __restrict__ edge_index, const float* __restrict__ ew,
        int* __restrict__ deg, float* __restrict__ scal,
        const float* __restrict__ Wproj, const float* __restrict__ bproj,
        const float* __restrict__ Wqkv, const float* __restrict__ bqkv,
        float* __restrict__ Wf, float* __restrict__ bfv,
        const float* __restrict__ W_edge, const float* __restrict__ att_edge,
        int* __restrict__ tbl) {
    int bid = blockIdx.x, tid = threadIdx.x;
    if (bid < GH_BLOCKS) {
        // ---- gat_h: 4 rows per wave, weights in regs ----
        int lane = tid & 63, wave = tid >> 6;
        int row0 = bid * 16 + wave * 4;
        float w0[16], w1[16];
#pragma unroll
        for (int f = 0; f < 16; f++) { w0[f] = W_gat[f * 128 + lane]; w1[f] = W_gat[f * 128 + 64 + lane]; }
        float as0 = att_src[lane], as1 = att_src[lane + 64];
        float ad0 = att_dst[lane], ad1 = att_dst[lane + 64];
#pragma unroll
        for (int r = 0; r < 4; r++) {
            int row = row0 + r;
            const float4* xr = (const float4*)(x + (long)row * 16);
            float4 xa = xr[0], xb = xr[1], xc = xr[2], xd = xr[3];
            float xv[16] = {xa.x, xa.y, xa.z, xa.w, xb.x, xb.y, xb.z, xb.w,
                            xc.x, xc.y, xc.z, xc.w, xd.x, xd.y, xd.z, xd.w};
            float h0 = 0.f, h1 = 0.f;
#pragma unroll
            for (int f = 0; f < 16; f++) { h0 += xv[f] * w0[f]; h1 += xv[f] * w1[f]; }
            h[(long)row * 128 + lane] = h0;
            h[(long)row * 128 + 64 + lane] = h1;
            float p0 = h0 * as0, p1 = h1 * as1;
            float q0 = h0 * ad0, q1 = h1 * ad1;
#pragma unroll
            for (int d = 1; d < 32; d <<= 1) {
                p0 += __shfl_xor(p0, d); p1 += __shfl_xor(p1, d);
                q0 += __shfl_xor(q0, d); q1 += __shfl_xor(q1, d);
            }
            if (lane == 0)  { a_src[row * 4 + 0] = p0; a_src[row * 4 + 2] = p1; a_dst[row * 4 + 0] = q0; a_dst[row * 4 + 2] = q1; }
            if (lane == 32) { a_src[row * 4 + 1] = p0; a_src[row * 4 + 3] = p1; a_dst[row * 4 + 1] = q0; a_dst[row * 4 + 3] = q1; }
        }
    } else if (bid < GH_BLOCKS + EH_BLOCKS) {
        // ---- ew-sum (atomic, raw sum) + in-degree histogram ----
        int e = (bid - GH_BLOCKS) * 256 + tid;
        float v = (e < EV) ? ew[e] : 0.f;
#pragma unroll
        for (int d = 32; d; d >>= 1) v += __shfl_xor(v, d);
        if ((tid & 63) == 0) atomicAdd(&scal[0], v);
        if (e < ETV) {
            int dst = (e < EV) ? edge_index[EV + e] : (e - EV);
            atomicAdd(&deg[dst], 1);
        }
    } else if (bid < GH_BLOCKS + EH_BLOCKS + FU_BLOCKS) {
        // ---- fuse: Wf = Wproj@Wqkv, bfv = bproj@Wqkv + bqkv ----
        int i = (bid - GH_BLOCKS - EH_BLOCKS) * 256 + tid;
        if (i < 32 * 192) {
            int c = i / 192, j = i - c * 192;
            float s = 0.f;
#pragma unroll
            for (int d = 0; d < 64; d++) s += Wproj[c * 64 + d] * Wqkv[d * 192 + j];
            Wf[i] = s;
        }
        if (i < 192) {
            float s = bqkv[i];
#pragma unroll
            for (int d = 0; d < 64; d++) s += bproj[d] * Wqkv[d * 192 + i];
            bfv[i] = s;
        }
    } else if (bid == GH_BLOCKS + EH_BLOCKS + FU_BLOCKS) {
        // ---- per-head edge-attention scalars (independent of ew sum) ----
        __shared__ float red[128];
        if (tid < 128) red[tid] = W_edge[tid] * att_edge[tid];
        __syncthreads();
        if (tid < 4) {
            float t = 0.f;
#pragma unroll
            for (int c = 0; c < 32; c++) t += red[tid * 32 + c];
            scal[1 + tid] = t;
        }
    } else {
        // ---- MFMA layout probe ----
        if (tid < 64) {
            int lane = tid;
            int quad = lane >> 4, L = lane & 15;
            short one = f2bf(1.0f), Ls = f2bf((float)L);
            bf16x8 ones, lv, alab;
#pragma unroll
            for (int j = 0; j < 8; j++) { ones[j] = one; lv[j] = Ls; alab[j] = f2bf((float)(quad * 8 + j)); }
            f32x4 zero = {0.f, 0.f, 0.f, 0.f};
            f32x4 dm = __builtin_amdgcn_mfma_f32_16x16x32_bf16(lv, ones, zero, 0, 0, 0);
            f32x4 dn = __builtin_amdgcn_mfma_f32_16x16x32_bf16(ones, lv, zero, 0, 0, 0);
#pragma unroll
            for (int r = 0; r < 4; r++) {
                tbl[lane * 4 + r]       = (int)(dm[r] * (1.f / 32.f) + 0.5f);
                tbl[256 + lane * 4 + r] = (int)(dn[r] * (1.f / 32.f) + 0.5f);
            }
            for (int b = 0; b < 32; b++) {
                bf16x8 bh;
#pragma unroll
                for (int j = 0; j < 8; j++) bh[j] = (quad == (b >> 3) && j == (b & 7)) ? one : (short)0;
                f32x4 d = __builtin_amdgcn_mfma_f32_16x16x32_bf16(alab, bh, zero, 0, 0, 0);
                int a = (int)(d[0] + 0.5f);
                if (lane == 0) tbl[512 + a] = b;
            }
        }
    }
}

// ---------------- Node B: scan (block 0) | pack W1/W2 (blocks 1..1024) ----------------
__global__ void scan_pack_kernel(const int* __restrict__ deg, int* __restrict__ rowptr, int* __restrict__ cnt,
                                 const float* __restrict__ W1, const float* __restrict__ W2,
                                 short* __restrict__ pw1, short* __restrict__ pw2,
                                 const int* __restrict__ tbl) {
    int bid = blockIdx.x, tid = threadIdx.x;
    if (bid == 0) {
        __shared__ int tot[256];
        int base = tid * 8;
        int local[8]; int s = 0;
        for (int i = 0; i < 8; i++) { int v = (base + i < NV) ? deg[base + i] : 0; local[i] = s; s += v; }
        tot[tid] = s; __syncthreads();
        for (int d = 1; d < 256; d <<= 1) {
            int v = (tid >= d) ? tot[tid - d] : 0;
            __syncthreads();
            tot[tid] += v;
            __syncthreads();
        }
        int ex = tot[tid] - s;
        for (int i = 0; i < 8; i++) {
            int idx = base + i;
            if (idx < NV) { int rp = ex + local[i]; rowptr[idx] = rp; cnt[idx] = rp; }
        }
        if (tid == 255) rowptr[NV] = tot[255];
    } else {
        int idx = (bid - 1) * 256 + tid;   // 0..262143
        if (idx < 131072) {
            int i = idx;
            int k = i >> 11, n = i & 2047;
            int s = k >> 5, kp = k & 31;
            int b = tbl[512 + kp];
            int lane = (b >> 3) * 16 + (n & 15), jj = b & 7;
            int t = n >> 4;
            pw1[(((t * 2 + s) * 64 + lane) << 3) + jj] = f2bf(W1[i]);
        } else {
            int i = idx - 131072;
            int k = i >> 6, n = i & 63;
            int kt = k >> 5, kp = k & 31;
            int b = tbl[512 + kp];
            int lane = (b >> 3) * 16 + (n & 15), jj = b & 7;
            int nt = n >> 4;
            pw2[(((kt * 4 + nt) * 64 + lane) << 3) + jj] = f2bf(W2[i]);
        }
    }
}

// ---------------- Node C: scatter edges into CSR (mean folded: scal[0] is raw sum) ----------------
__global__ void scatter_kernel(const int* __restrict__ edge_index, const float* __restrict__ edge_weight,
                               const float* __restrict__ scal, int* __restrict__ cnt,
                               int* __restrict__ csr_src, float* __restrict__ csr_ew) {
    int e = blockIdx.x * 256 + threadIdx.x;
    if (e >= ETV) return;
    int src, dst; float w;
    if (e < EV) { src = edge_index[e]; dst = edge_index[EV + e]; w = edge_weight[e]; }
    else        { src = dst = e - EV; w = scal[0] * (1.f / (float)EV); }
    int pos = atomicAdd(&cnt[dst], 1);
    csr_src[pos] = src; csr_ew[pos] = w;
}

// ---------------- Node D: segment softmax + aggregation + head mean -> outg (32 ch) ----------------
// 16000 blocks, XCD-swizzled; one wave per (g,n); per-wave LDS staging, no block syncs.
__global__ __launch_bounds__(256) void gat_agg_kernel(const float* __restrict__ h, const float* __restrict__ a_src,
                                                      const float* __restrict__ a_dst, const int* __restrict__ rowptr,
                                                      const int* __restrict__ csr_src, const float* __restrict__ csr_ew,
                                                      const float* __restrict__ scal, const float* __restrict__ gat_bias,
                                                      float* __restrict__ outg) {
    __shared__ int   ssrc[4][64];
    __shared__ float swt[4][4][65];
    int tid = threadIdx.x;
    int lane = tid & 63, wave = tid >> 6;
    int bid = blockIdx.x;
    int xcd = bid & 7, j = bid >> 3;
    int g = xcd * 4 + j / 500;
    int n = (j % 500) * 4 + wave;
    int w = g * NV + n;
    float s0 = scal[1], s1 = scal[2], s2 = scal[3], s3 = scal[4];
    const float4 ad = *(const float4*)(a_dst + (long)w * 4);
    const float* asrc_g = a_src + (long)g * NV * 4;
    const float* hg = h + (long)g * NV * 128;
    int start = rowptr[n], end = rowptr[n + 1];
    int half = lane >> 5, c = lane & 31;
    int hsel = c >> 3;
    float den0 = 0.f, den1 = 0.f, den2 = 0.f, den3 = 0.f;
    float4 msg = {0.f, 0.f, 0.f, 0.f};
    for (int base = start; base < end; base += 64) {
        int idx = base + lane;
        int se = 0; float e0 = 0.f, e1 = 0.f, e2 = 0.f, e3 = 0.f;
        if (idx < end) {
            se = csr_src[idx]; float ew = csr_ew[idx];
            float4 as = *(const float4*)(asrc_g + se * 4);
            float l0 = as.x + ad.x + ew * s0; l0 = l0 > 0.f ? l0 : 0.2f * l0; e0 = __expf(l0);
            float l1 = as.y + ad.y + ew * s1; l1 = l1 > 0.f ? l1 : 0.2f * l1; e1 = __expf(l1);
            float l2 = as.z + ad.z + ew * s2; l2 = l2 > 0.f ? l2 : 0.2f * l2; e2 = __expf(l2);
            float l3 = as.w + ad.w + ew * s3; l3 = l3 > 0.f ? l3 : 0.2f * l3; e3 = __expf(l3);
            den0 += e0; den1 += e1; den2 += e2; den3 += e3;
        }
        ssrc[wave][lane] = se;
        swt[wave][0][lane] = e0; swt[wave][1][lane] = e1;
        swt[wave][2][lane] = e2; swt[wave][3][lane] = e3;
        __builtin_amdgcn_wave_barrier();
        int cn = end - base; if (cn > 64) cn = 64;
        int npairs = (cn + 1) >> 1;
#pragma unroll 4
        for (int i = 0; i < npairs; i++) {
            int slot = 2 * i + half;
            int sse = ssrc[wave][slot];
            float wt = swt[wave][hsel][slot];          // staged 0 for slots >= cn
            const float4 hv = *(const float4*)(hg + (long)sse * 128 + c * 4);
            msg.x += wt * hv.x; msg.y += wt * hv.y; msg.z += wt * hv.z; msg.w += wt * hv.w;
        }
        __builtin_amdgcn_wave_barrier();
    }
#pragma unroll
    for (int d = 32; d; d >>= 1) {
        den0 += __shfl_xor(den0, d); den1 += __shfl_xor(den1, d);
        den2 += __shfl_xor(den2, d); den3 += __shfl_xor(den3, d);
    }
    float denh = (hsel == 0) ? den0 : (hsel == 1) ? den1 : (hsel == 2) ? den2 : den3;
    float inv = 1.f / (denh + 1e-16f);
    msg.x *= inv; msg.y *= inv; msg.z *= inv; msg.w *= inv;
    // combine edge halves, then head mean (c bits 3,4)
    msg.x += __shfl_xor(msg.x, 32); msg.y += __shfl_xor(msg.y, 32);
    msg.z += __shfl_xor(msg.z, 32); msg.w += __shfl_xor(msg.w, 32);
    msg.x += __shfl_xor(msg.x, 8);  msg.y += __shfl_xor(msg.y, 8);
    msg.z += __shfl_xor(msg.z, 8);  msg.w += __shfl_xor(msg.w, 8);
    msg.x += __shfl_xor(msg.x, 16); msg.y += __shfl_xor(msg.y, 16);
    msg.z += __shfl_xor(msg.z, 16); msg.w += __shfl_xor(msg.w, 16);
    if (half == 0 && c < 8) {
        const float4 gb = *(const float4*)(gat_bias + c * 4);
        float4 o;
        o.x = 0.25f * msg.x + gb.x; o.y = 0.25f * msg.y + gb.y;
        o.z = 0.25f * msg.z + gb.z; o.w = 0.25f * msg.w + gb.w;
        int b = g / TV, tt = g - b * TV;
        *(float4*)(outg + (((long)(b * NV + n)) * TV + tt) * 32 + c * 4) = o;
    }
}

// ---------------- Node E: fused qkv (K=32) + attention + Wo + LN1 -> z1 ----------------
__global__ __launch_bounds__(256) void attn_kernel(const float* __restrict__ og, const float* __restrict__ Wf,
                                                   const float* __restrict__ bfv, const float* __restrict__ Wproj,
                                                   const float* __restrict__ bproj, const float* __restrict__ Wo,
                                                   const float* __restrict__ bo, const float* __restrict__ ln1g,
                                                   const float* __restrict__ ln1b, float* __restrict__ z1) {
    __shared__ float ot[512], wkvf[4096], kb[1024], vb[1024], qv[64], pv[64], sc[64], yv[64];
    int tid = threadIdx.x;
    int bn = blockIdx.x;
    const float* ob = og + (long)bn * 512;
    for (int i = tid; i < 512; i += 256) ot[i] = ob[i];
    for (int i = tid; i < 4096; i += 256) { int d = i >> 7, j = i & 127; wkvf[i] = Wf[d * 192 + 64 + j]; }
    __syncthreads();
    {
        int j = tid & 127, tb = tid >> 7;
        float wcol[32];
#pragma unroll
        for (int d = 0; d < 32; d++) wcol[d] = wkvf[d * 128 + j];
        float bias = bfv[64 + j];
#pragma unroll
        for (int k = 0; k < 8; k++) {
            int t = 2 * k + tb;
            const float* orow = &ot[t * 32];
            float a = bias;
#pragma unroll
            for (int d = 0; d < 32; d++) a += orow[d] * wcol[d];
            if (j < 64) kb[t * 64 + j] = a; else vb[t * 64 + (j - 64)] = a;
        }
    }
    if (tid < 64) {
        float a = bfv[tid];
        float yr = bproj[tid];
#pragma unroll
        for (int d = 0; d < 32; d++) {
            float od = ot[15 * 32 + d];
            a  += od * Wf[d * 192 + tid];
            yr += od * Wproj[d * 64 + tid];
        }
        qv[tid] = a; yv[tid] = yr;
    }
    __syncthreads();
    if (tid < 64) {
        int hh = tid >> 4, t = tid & 15;
        float s = 0.f;
#pragma unroll
        for (int dd = 0; dd < 16; dd++) s += qv[hh * 16 + dd] * kb[t * 64 + hh * 16 + dd];
        sc[tid] = s * 0.25f;
    }
    __syncthreads();
    if (tid < 64) {
        int hh = tid >> 4;
        float m = -INFINITY;
        for (int t = 0; t < 16; t++) m = fmaxf(m, sc[hh * 16 + t]);
        float den = 0.f;
        for (int t = 0; t < 16; t++) den += __expf(sc[hh * 16 + t] - m);
        pv[tid] = __expf(sc[tid] - m) / den;
    }
    __syncthreads();
    if (tid < 64) {
        int hh = tid >> 4;
        float ctx = 0.f;
#pragma unroll
        for (int t = 0; t < 16; t++) ctx += pv[hh * 16 + t] * vb[t * 64 + tid];
        sc[tid] = ctx;
    }
    __syncthreads();
    if (tid < 64) {
        float o = bo[tid];
#pragma unroll
        for (int j = 0; j < 64; j++) o += sc[j] * Wo[j * 64 + tid];
        float r = yv[tid] + o;
        float sum = r, sq = r * r;
#pragma unroll
        for (int d = 32; d; d >>= 1) { sum += __shfl_xor(sum, d); sq += __shfl_xor(sq, d); }
        float mu = sum * (1.f / 64.f);
        float var = sq * (1.f / 64.f) - mu * mu;
        float zz = (r - mu) * rsqrtf(var + 1e-5f) * ln1g[tid] + ln1b[tid];
        z1[(long)bn * 64 + tid] = zz;
    }
}

// ---------------- Node F: FF via bf16 MFMA (layout-table-driven) + residual + LN2 -> out ----------------
__global__ __launch_bounds__(256) void ff_mfma_kernel(const float* __restrict__ z1,
        const short* __restrict__ pw1, const short* __restrict__ pw2,
        const float* __restrict__ b1, const float* __restrict__ b2,
        const float* __restrict__ ln2g, const float* __restrict__ ln2b,
        const int* __restrict__ tbl, float* __restrict__ out) {
    __shared__ __align__(16) short zb[16 * 72];
    __shared__ __align__(16) short hb[4][16 * 520];
    __shared__ float part[4 * 16 * 64];
    int tid = threadIdx.x;
    int row0 = blockIdx.x * 16;
    for (int i = tid; i < 1024; i += 256)
        zb[(i >> 6) * 72 + (i & 63)] = f2bf(z1[(long)row0 * 64 + i]);
    __syncthreads();
    int lane = tid & 63, wv = tid >> 6;
    int quad = lane >> 4, m16 = lane & 15;
    int mo[4], no[4];
#pragma unroll
    for (int r = 0; r < 4; r++) { mo[r] = tbl[lane * 4 + r]; no[r] = tbl[256 + lane * 4 + r]; }
    bf16x8 a0 = *(const bf16x8*)&zb[m16 * 72 + quad * 8];
    bf16x8 a1 = *(const bf16x8*)&zb[m16 * 72 + 32 + quad * 8];
    const short* pb1 = pw1 + (size_t)wv * 32 * 2 * 512;
    short* hbw = &hb[wv][0];
#pragma unroll 4
    for (int t = 0; t < 32; t++) {
        bf16x8 bA = *(const bf16x8*)(pb1 + ((t * 2 + 0) << 9) + (lane << 3));
        bf16x8 bB = *(const bf16x8*)(pb1 + ((t * 2 + 1) << 9) + (lane << 3));
        f32x4 acc = {0.f, 0.f, 0.f, 0.f};
        acc = __builtin_amdgcn_mfma_f32_16x16x32_bf16(a0, bA, acc, 0, 0, 0);
        acc = __builtin_amdgcn_mfma_f32_16x16x32_bf16(a1, bB, acc, 0, 0, 0);
#pragma unroll
        for (int r = 0; r < 4; r++) {
            float v = acc[r] + b1[wv * 512 + t * 16 + no[r]];
            v = v > 0.f ? v : 0.f;
            hbw[mo[r] * 520 + t * 16 + no[r]] = f2bf(v);
        }
    }
    __syncthreads();
    f32x4 acc2[4] = {{0.f,0.f,0.f,0.f},{0.f,0.f,0.f,0.f},{0.f,0.f,0.f,0.f},{0.f,0.f,0.f,0.f}};
    const short* pb2 = pw2 + (size_t)wv * 16 * 4 * 512;
#pragma unroll 2
    for (int kt = 0; kt < 16; kt++) {
        bf16x8 af = *(const bf16x8*)&hbw[m16 * 520 + kt * 32 + quad * 8];
#pragma unroll
        for (int nt = 0; nt < 4; nt++) {
            bf16x8 bfr = *(const bf16x8*)(pb2 + ((kt * 4 + nt) << 9) + (lane << 3));
            acc2[nt] = __builtin_amdgcn_mfma_f32_16x16x32_bf16(af, bfr, acc2[nt], 0, 0, 0);
        }
    }
#pragma unroll
    for (int nt = 0; nt < 4; nt++)
#pragma unroll
        for (int r = 0; r < 4; r++)
            part[wv * 1024 + mo[r] * 64 + nt * 16 + no[r]] = acc2[nt][r];
    __syncthreads();
    int col = tid & 63, rq = tid >> 6;
    float g = ln2g[col], bb = ln2b[col], bias2 = b2[col];
#pragma unroll
    for (int k2 = 0; k2 < 4; k2++) {
        int r = rq + k2 * 4;
        float val = part[r * 64 + col] + part[1024 + r * 64 + col]
                  + part[2048 + r * 64 + col] + part[3072 + r * 64 + col]
                  + z1[(long)(row0 + r) * 64 + col] + bias2;
        float sum = val, sq = val * val;
#pragma unroll
        for (int dlt = 32; dlt; dlt >>= 1) { sum += __shfl_xor(sum, dlt); sq += __shfl_xor(sq, dlt); }
        float mu = sum * (1.f / 64.f);
        float var = sq * (1.f / 64.f) - mu * mu;
        out[(long)(row0 + r) * 64 + col] = (val - mu) * rsqrtf(var + 1e-5f) * g + bb;
    }
}

extern "C" void kernel_launch(void* const* d_in, const int* in_sizes, int n_in,
                              void* d_out, int out_size, void* d_ws, size_t ws_size,
                              hipStream_t stream) {
    const float* x_seq      = (const float*)d_in[0];
    const int*   edge_index = (const int*)  d_in[1];
    const float* edge_weight= (const float*)d_in[2];
    const float* W_gat      = (const float*)d_in[3];
    const float* att_src    = (const float*)d_in[4];
    const float* att_dst    = (const float*)d_in[5];
    const float* W_edge     = (const float*)d_in[6];
    const float* att_edge   = (const float*)d_in[7];
    const float* gat_bias   = (const float*)d_in[8];
    const float* W_proj     = (const float*)d_in[9];
    const float* b_proj     = (const float*)d_in[10];
    const float* Wqkv       = (const float*)d_in[11];
    const float* bqkv       = (const float*)d_in[12];
    const float* Wo         = (const float*)d_in[13];
    const float* bo         = (const float*)d_in[14];
    const float* ln1g       = (const float*)d_in[15];
    const float* ln1b       = (const float*)d_in[16];
    const float* W1         = (const float*)d_in[17];
    const float* b1         = (const float*)d_in[18];
    const float* W2         = (const float*)d_in[19];
    const float* b2         = (const float*)d_in[20];
    const float* ln2g       = (const float*)d_in[21];
    const float* ln2b       = (const float*)d_in[22];
    float* outp = (float*)d_out;

    float* wsf = (float*)d_ws;
    float* h      = wsf + OFF_H;
    float* a_src  = wsf + OFF_ASRC;
    float* a_dst  = wsf + OFF_ADST;
    float* outg   = wsf + OFF_Y;
    float* Wfused = wsf + OFF_WF;
    float* bfv    = Wfused + 32 * 192;
    float* z1     = wsf + OFF_Z1;
    float* scal   = wsf + OFF_SCAL;
    int*   cnt    = (int*)(wsf + OFF_SCAL + 16);
    int*   rowptr = cnt + 2000;
    int*   csr_src= rowptr + 2001;
    float* csr_ew = (float*)(csr_src + 34000);
    short* pw1    = (short*)(wsf + OFF_PACK);
    short* pw2    = pw1 + 131072;
    int*   tbl    = (int*)(wsf + OFF_TBL);

    // one memset covers scal[16] + cnt[2000]
    hipMemsetAsync(scal, 0, (16 + NV) * sizeof(float), stream);
    mega_kernel<<<GH_BLOCKS + EH_BLOCKS + FU_BLOCKS + 2, 256, 0, stream>>>(
        x_seq, W_gat, att_src, att_dst, h, a_src, a_dst,
        edge_index, edge_weight, cnt, scal,
        W_proj, b_proj, Wqkv, bqkv, Wfused, bfv, W_edge, att_edge, tbl);
    scan_pack_kernel<<<1025, 256, 0, stream>>>(cnt, rowptr, cnt, W1, W2, pw1, pw2, tbl);
    scatter_kernel<<<(ETV + 255) / 256, 256, 0, stream>>>(edge_index, edge_weight, scal, cnt,
                                                          csr_src, csr_ew);
    gat_agg_kernel<<<GV * NV / 4, 256, 0, stream>>>(h, a_src, a_dst, rowptr, csr_src, csr_ew, scal,
                                                    gat_bias, outg);
    attn_kernel<<<BV * NV, 256, 0, stream>>>(outg, Wfused, bfv, W_proj, b_proj, Wo, bo, ln1g, ln1b, z1);
    ff_mfma_kernel<<<BV * NV / 16, 256, 0, stream>>>(z1, pw1, pw2, b1, b2, ln2g, ln2b, tbl, outp);
}

// Round 12
// 217.295 us; speedup vs baseline: 2.2227x; 1.0064x over previous
//
#include <hip/hip_runtime.h>
#include <math.h>

#define BV 2
#define TV 16
#define NV 2000
#define FIN 16
#define EV 32000
#define ETV 34000
#define GV 32
#define DD 64
#define FFV 2048

// workspace layout (float offsets)
#define OFF_H     0L          // h fp32 [32*2000*128]
#define OFF_ASRC  8192000L
#define OFF_ADST  8448000L
#define OFF_Y     8704000L    // outg [2*2000*16*32]
#define OFF_WF    10752000L   // fused Wf [32*192], bfv [192]
#define OFF_Z1    12800000L
#define OFF_SCAL  13056000L   // scal[16], cnt[2000], rowptr[2001], csr_src[34000], csr_ew[34000]
#define OFF_PACK  19000000L   // pw1 [131072 bf16], pw2 [131072 bf16]
#define OFF_TBL   19400000L   // int tbl[544]

// node-A block ranges
#define GH_BLOCKS 4000        // gat_h
#define EH_BLOCKS 133         // ew-sum + hist
#define FU_BLOCKS 24          // fuse

typedef __attribute__((ext_vector_type(8))) short bf16x8;
typedef __attribute__((ext_vector_type(4))) float f32x4;

__device__ __forceinline__ short f2bf(float f) {
    union { float f; unsigned u; } v; v.f = f;
    unsigned r = v.u + 0x7FFFu + ((v.u >> 16) & 1u);   // round-to-nearest-even
    return (short)(r >> 16);
}

// ---------------- Node A: gat_h | ew-sum+hist | fuse | head-scalars | MFMA probe ----------------
__global__ __launch_bounds__(256) void mega_kernel(const float* __restrict__ x, const float* __restrict__ W_gat,
        const float* __restrict__ att_src, const float* __restrict__ att_dst,
        float* __restrict__ h, float* __restrict__ a_src, float* __restrict__ a_dst,
        const int* __restrict__ edge_index, const float* __restrict__ ew,
        int* __restrict__ deg, float* __restrict__ scal,
        const float* __restrict__ Wproj, const float* __restrict__ bproj,
        const float* __restrict__ Wqkv, const float* __restrict__ bqkv,
        float* __restrict__ Wf, float* __restrict__ bfv,
        const float* __restrict__ W_edge, const float* __restrict__ att_edge,
        int* __restrict__ tbl) {
    int bid = blockIdx.x, tid = threadIdx.x;
    if (bid < GH_BLOCKS) {
        int lane = tid & 63, wave = tid >> 6;
        int row0 = bid * 16 + wave * 4;
        float w0[16], w1[16];
#pragma unroll
        for (int f = 0; f < 16; f++) { w0[f] = W_gat[f * 128 + lane]; w1[f] = W_gat[f * 128 + 64 + lane]; }
        float as0 = att_src[lane], as1 = att_src[lane + 64];
        float ad0 = att_dst[lane], ad1 = att_dst[lane + 64];
#pragma unroll
        for (int r = 0; r < 4; r++) {
            int row = row0 + r;
            const float4* xr = (const float4*)(x + (long)row * 16);
            float4 xa = xr[0], xb = xr[1], xc = xr[2], xd = xr[3];
            float xv[16] = {xa.x, xa.y, xa.z, xa.w, xb.x, xb.y, xb.z, xb.w,
                            xc.x, xc.y, xc.z, xc.w, xd.x, xd.y, xd.z, xd.w};
            float h0 = 0.f, h1 = 0.f;
#pragma unroll
            for (int f = 0; f < 16; f++) { h0 += xv[f] * w0[f]; h1 += xv[f] * w1[f]; }
            h[(long)row * 128 + lane] = h0;
            h[(long)row * 128 + 64 + lane] = h1;
            float p0 = h0 * as0, p1 = h1 * as1;
            float q0 = h0 * ad0, q1 = h1 * ad1;
#pragma unroll
            for (int d = 1; d < 32; d <<= 1) {
                p0 += __shfl_xor(p0, d); p1 += __shfl_xor(p1, d);
                q0 += __shfl_xor(q0, d); q1 += __shfl_xor(q1, d);
            }
            if (lane == 0)  { a_src[row * 4 + 0] = p0; a_src[row * 4 + 2] = p1; a_dst[row * 4 + 0] = q0; a_dst[row * 4 + 2] = q1; }
            if (lane == 32) { a_src[row * 4 + 1] = p0; a_src[row * 4 + 3] = p1; a_dst[row * 4 + 1] = q0; a_dst[row * 4 + 3] = q1; }
        }
    } else if (bid < GH_BLOCKS + EH_BLOCKS) {
        int e = (bid - GH_BLOCKS) * 256 + tid;
        float v = (e < EV) ? ew[e] : 0.f;
#pragma unroll
        for (int d = 32; d; d >>= 1) v += __shfl_xor(v, d);
        if ((tid & 63) == 0) atomicAdd(&scal[0], v);
        if (e < ETV) {
            int dst = (e < EV) ? edge_index[EV + e] : (e - EV);
            atomicAdd(&deg[dst], 1);
        }
    } else if (bid < GH_BLOCKS + EH_BLOCKS + FU_BLOCKS) {
        int i = (bid - GH_BLOCKS - EH_BLOCKS) * 256 + tid;
        if (i < 32 * 192) {
            int c = i / 192, j = i - c * 192;
            float s = 0.f;
#pragma unroll
            for (int d = 0; d < 64; d++) s += Wproj[c * 64 + d] * Wqkv[d * 192 + j];
            Wf[i] = s;
        }
        if (i < 192) {
            float s = bqkv[i];
#pragma unroll
            for (int d = 0; d < 64; d++) s += bproj[d] * Wqkv[d * 192 + i];
            bfv[i] = s;
        }
    } else if (bid == GH_BLOCKS + EH_BLOCKS + FU_BLOCKS) {
        __shared__ float red[128];
        if (tid < 128) red[tid] = W_edge[tid] * att_edge[tid];
        __syncthreads();
        if (tid < 4) {
            float t = 0.f;
#pragma unroll
            for (int c = 0; c < 32; c++) t += red[tid * 32 + c];
            scal[1 + tid] = t;
        }
    } else {
        if (tid < 64) {
            int lane = tid;
            int quad = lane >> 4, L = lane & 15;
            short one = f2bf(1.0f), Ls = f2bf((float)L);
            bf16x8 ones, lv, alab;
#pragma unroll
            for (int j = 0; j < 8; j++) { ones[j] = one; lv[j] = Ls; alab[j] = f2bf((float)(quad * 8 + j)); }
            f32x4 zero = {0.f, 0.f, 0.f, 0.f};
            f32x4 dm = __builtin_amdgcn_mfma_f32_16x16x32_bf16(lv, ones, zero, 0, 0, 0);
            f32x4 dn = __builtin_amdgcn_mfma_f32_16x16x32_bf16(ones, lv, zero, 0, 0, 0);
#pragma unroll
            for (int r = 0; r < 4; r++) {
                tbl[lane * 4 + r]       = (int)(dm[r] * (1.f / 32.f) + 0.5f);
                tbl[256 + lane * 4 + r] = (int)(dn[r] * (1.f / 32.f) + 0.5f);
            }
            for (int b = 0; b < 32; b++) {
                bf16x8 bh;
#pragma unroll
                for (int j = 0; j < 8; j++) bh[j] = (quad == (b >> 3) && j == (b & 7)) ? one : (short)0;
                f32x4 d = __builtin_amdgcn_mfma_f32_16x16x32_bf16(alab, bh, zero, 0, 0, 0);
                int a = (int)(d[0] + 0.5f);
                if (lane == 0) tbl[512 + a] = b;
            }
        }
    }
}

// ---------------- Node B: scan (block 0) | pack W1/W2 (blocks 1..1024) ----------------
__global__ void scan_pack_kernel(const int* __restrict__ deg, int* __restrict__ rowptr, int* __restrict__ cnt,
                                 const float* __restrict__ W1, const float* __restrict__ W2,
                                 short* __restrict__ pw1, short* __restrict__ pw2,
                                 const int* __restrict__ tbl) {
    int bid = blockIdx.x, tid = threadIdx.x;
    if (bid == 0) {
        __shared__ int tot[256];
        int base = tid * 8;
        int local[8]; int s = 0;
        for (int i = 0; i < 8; i++) { int v = (base + i < NV) ? deg[base + i] : 0; local[i] = s; s += v; }
        tot[tid] = s; __syncthreads();
        for (int d = 1; d < 256; d <<= 1) {
            int v = (tid >= d) ? tot[tid - d] : 0;
            __syncthreads();
            tot[tid] += v;
            __syncthreads();
        }
        int ex = tot[tid] - s;
        for (int i = 0; i < 8; i++) {
            int idx = base + i;
            if (idx < NV) { int rp = ex + local[i]; rowptr[idx] = rp; cnt[idx] = rp; }
        }
        if (tid == 255) rowptr[NV] = tot[255];
    } else {
        int idx = (bid - 1) * 256 + tid;   // 0..262143
        if (idx < 131072) {
            int i = idx;
            int k = i >> 11, n = i & 2047;
            int s = k >> 5, kp = k & 31;
            int b = tbl[512 + kp];
            int lane = (b >> 3) * 16 + (n & 15), jj = b & 7;
            int t = n >> 4;
            pw1[(((t * 2 + s) * 64 + lane) << 3) + jj] = f2bf(W1[i]);
        } else {
            int i = idx - 131072;
            int k = i >> 6, n = i & 63;
            int kt = k >> 5, kp = k & 31;
            int b = tbl[512 + kp];
            int lane = (b >> 3) * 16 + (n & 15), jj = b & 7;
            int nt = n >> 4;
            pw2[(((kt * 4 + nt) * 64 + lane) << 3) + jj] = f2bf(W2[i]);
        }
    }
}

// ---------------- Node C: scatter edges into CSR (mean folded: scal[0] is raw sum) ----------------
__global__ void scatter_kernel(const int* __restrict__ edge_index, const float* __restrict__ edge_weight,
                               const float* __restrict__ scal, int* __restrict__ cnt,
                               int* __restrict__ csr_src, float* __restrict__ csr_ew) {
    int e = blockIdx.x * 256 + threadIdx.x;
    if (e >= ETV) return;
    int src, dst; float w;
    if (e < EV) { src = edge_index[e]; dst = edge_index[EV + e]; w = edge_weight[e]; }
    else        { src = dst = e - EV; w = scal[0] * (1.f / (float)EV); }
    int pos = atomicAdd(&cnt[dst], 1);
    csr_src[pos] = src; csr_ew[pos] = w;
}

// ---------------- Node D: segment softmax + aggregation + head mean -> outg ----------------
// 8000 blocks, XCD-swizzled. Each wave serves TWO nodes (one per 32-lane half):
// half = lane>>5 selects the node; hl = lane&31 selects 4 channels (hl*4..hl*4+3, head hl>>3).
// Exp phase packs both nodes' edges (32 slots each); epilogue reductions stay within a half.
__global__ __launch_bounds__(256) void gat_agg_kernel(const float* __restrict__ h, const float* __restrict__ a_src,
                                                      const float* __restrict__ a_dst, const int* __restrict__ rowptr,
                                                      const int* __restrict__ csr_src, const float* __restrict__ csr_ew,
                                                      const float* __restrict__ scal, const float* __restrict__ gat_bias,
                                                      float* __restrict__ outg) {
    __shared__ int   ssrc[4][64];
    __shared__ float swt[4][4][64];
    int tid = threadIdx.x;
    int lane = tid & 63, wave = tid >> 6;
    int bid = blockIdx.x;
    int xcd = bid & 7, j = bid >> 3;          // j in [0,1000)
    int g = xcd * 4 + j / 250;
    int pr = (j % 250) * 4 + wave;            // pair index [0,1000)
    int half = lane >> 5, hl = lane & 31;
    int n = pr * 2 + half;                    // this half's node
    float s0 = scal[1], s1 = scal[2], s2 = scal[3], s3 = scal[4];
    const float4 ad = *(const float4*)(a_dst + ((long)g * NV + n) * 4);
    const float* asrc_g = a_src + (long)g * NV * 4;
    const float* hg = h + (long)g * NV * 128;
    int start = rowptr[n], end = rowptr[n + 1];
    int deg = end - start;
    int degmax = max(deg, __shfl_xor(deg, 32));
    int hsel = hl >> 3;                       // head of this lane's 4 channels
    float den0 = 0.f, den1 = 0.f, den2 = 0.f, den3 = 0.f;
    float4 msg = {0.f, 0.f, 0.f, 0.f};
    for (int base = 0; base < degmax; base += 32) {
        int idx = start + base + hl;
        int se = 0; float e0 = 0.f, e1 = 0.f, e2 = 0.f, e3 = 0.f;
        if (idx < end) {
            se = csr_src[idx]; float ew = csr_ew[idx];
            float4 as = *(const float4*)(asrc_g + se * 4);
            float l0 = as.x + ad.x + ew * s0; l0 = l0 > 0.f ? l0 : 0.2f * l0; e0 = __expf(l0);
            float l1 = as.y + ad.y + ew * s1; l1 = l1 > 0.f ? l1 : 0.2f * l1; e1 = __expf(l1);
            float l2 = as.z + ad.z + ew * s2; l2 = l2 > 0.f ? l2 : 0.2f * l2; e2 = __expf(l2);
            float l3 = as.w + ad.w + ew * s3; l3 = l3 > 0.f ? l3 : 0.2f * l3; e3 = __expf(l3);
            den0 += e0; den1 += e1; den2 += e2; den3 += e3;
        }
        ssrc[wave][lane] = se;
        swt[wave][0][lane] = e0; swt[wave][1][lane] = e1;
        swt[wave][2][lane] = e2; swt[wave][3][lane] = e3;
        __builtin_amdgcn_wave_barrier();
        int cn = deg - base; cn = cn < 0 ? 0 : (cn > 32 ? 32 : cn);
        const int*   sp = &ssrc[wave][half * 32];
        const float* wp = &swt[wave][hsel][half * 32];
#pragma unroll 4
        for (int s = 0; s < cn; s++) {
            int sse = sp[s];
            float wt = wp[s];
            const float4 hv = *(const float4*)(hg + (long)sse * 128 + hl * 4);
            msg.x += wt * hv.x; msg.y += wt * hv.y; msg.z += wt * hv.z; msg.w += wt * hv.w;
        }
        __builtin_amdgcn_wave_barrier();
    }
    // den butterfly within the half (xor < 32 stays inside)
#pragma unroll
    for (int d = 16; d; d >>= 1) {
        den0 += __shfl_xor(den0, d); den1 += __shfl_xor(den1, d);
        den2 += __shfl_xor(den2, d); den3 += __shfl_xor(den3, d);
    }
    float denh = (hsel == 0) ? den0 : (hsel == 1) ? den1 : (hsel == 2) ? den2 : den3;
    float inv = 1.f / (denh + 1e-16f);
    msg.x *= inv; msg.y *= inv; msg.z *= inv; msg.w *= inv;
    // head mean over hl bits 3,4 (stays within half)
    msg.x += __shfl_xor(msg.x, 8);  msg.y += __shfl_xor(msg.y, 8);
    msg.z += __shfl_xor(msg.z, 8);  msg.w += __shfl_xor(msg.w, 8);
    msg.x += __shfl_xor(msg.x, 16); msg.y += __shfl_xor(msg.y, 16);
    msg.z += __shfl_xor(msg.z, 16); msg.w += __shfl_xor(msg.w, 16);
    if (hl < 8) {
        const float4 gb = *(const float4*)(gat_bias + hl * 4);
        float4 o;
        o.x = 0.25f * msg.x + gb.x; o.y = 0.25f * msg.y + gb.y;
        o.z = 0.25f * msg.z + gb.z; o.w = 0.25f * msg.w + gb.w;
        int b = g / TV, tt = g - b * TV;
        *(float4*)(outg + (((long)(b * NV + n)) * TV + tt) * 32 + hl * 4) = o;
    }
}

// ---------------- Node E: fused qkv (K=32) + attention + Wo + LN1 -> z1 ----------------
// kv phase uses all 4 waves; the serial tail is wave-0-only with wave-internal ordering.
__global__ __launch_bounds__(256) void attn_kernel(const float* __restrict__ og, const float* __restrict__ Wf,
                                                   const float* __restrict__ bfv, const float* __restrict__ Wproj,
                                                   const float* __restrict__ bproj, const float* __restrict__ Wo,
                                                   const float* __restrict__ bo, const float* __restrict__ ln1g,
                                                   const float* __restrict__ ln1b, float* __restrict__ z1) {
    __shared__ float ot[512], wkvf[4096], kb[1024], vb[1024], qv[64], pv[64], sc[64];
    int tid = threadIdx.x;
    int bn = blockIdx.x;
    const float* ob = og + (long)bn * 512;
    for (int i = tid; i < 512; i += 256) ot[i] = ob[i];
    for (int i = tid; i < 4096; i += 256) { int d = i >> 7, j = i & 127; wkvf[i] = Wf[d * 192 + 64 + j]; }
    __syncthreads();
    {
        int j = tid & 127, tb = tid >> 7;
        float wcol[32];
#pragma unroll
        for (int d = 0; d < 32; d++) wcol[d] = wkvf[d * 128 + j];
        float bias = bfv[64 + j];
#pragma unroll
        for (int k = 0; k < 8; k++) {
            int t = 2 * k + tb;
            const float* orow = &ot[t * 32];
            float a = bias;
#pragma unroll
            for (int d = 0; d < 32; d++) a += orow[d] * wcol[d];
            if (j < 64) kb[t * 64 + j] = a; else vb[t * 64 + (j - 64)] = a;
        }
    }
    __syncthreads();
    if (tid < 64) {
        // q + residual y (registers)
        float a = bfv[tid];
        float yr = bproj[tid];
#pragma unroll
        for (int d = 0; d < 32; d++) {
            float od = ot[15 * 32 + d];
            a  += od * Wf[d * 192 + tid];
            yr += od * Wproj[d * 64 + tid];
        }
        qv[tid] = a;
        __builtin_amdgcn_wave_barrier();
        // scores
        int hh = tid >> 4, t = tid & 15;
        float s = 0.f;
#pragma unroll
        for (int dd = 0; dd < 16; dd++) s += qv[hh * 16 + dd] * kb[t * 64 + hh * 16 + dd];
        sc[tid] = s * 0.25f;
        __builtin_amdgcn_wave_barrier();
        // softmax per head
        float m = -INFINITY;
        for (int t2 = 0; t2 < 16; t2++) m = fmaxf(m, sc[hh * 16 + t2]);
        float den = 0.f;
        for (int t2 = 0; t2 < 16; t2++) den += __expf(sc[hh * 16 + t2] - m);
        pv[tid] = __expf(sc[tid] - m) / den;
        __builtin_amdgcn_wave_barrier();
        // ctx
        float ctx = 0.f;
#pragma unroll
        for (int t2 = 0; t2 < 16; t2++) ctx += pv[hh * 16 + t2] * vb[t2 * 64 + tid];
        sc[tid] = ctx;
        __builtin_amdgcn_wave_barrier();
        // Wo + residual + LN1
        float o = bo[tid];
#pragma unroll
        for (int j = 0; j < 64; j++) o += sc[j] * Wo[j * 64 + tid];
        float r = yr + o;
        float sum = r, sq = r * r;
#pragma unroll
        for (int d = 32; d; d >>= 1) { sum += __shfl_xor(sum, d); sq += __shfl_xor(sq, d); }
        float mu = sum * (1.f / 64.f);
        float var = sq * (1.f / 64.f) - mu * mu;
        float zz = (r - mu) * rsqrtf(var + 1e-5f) * ln1g[tid] + ln1b[tid];
        z1[(long)bn * 64 + tid] = zz;
    }
}

// ---------------- Node F: FF via bf16 MFMA (layout-table-driven) + residual + LN2 -> out ----------------
__global__ __launch_bounds__(256) void ff_mfma_kernel(const float* __restrict__ z1,
        const short* __restrict__ pw1, const short* __restrict__ pw2,
        const float* __restrict__ b1, const float* __restrict__ b2,
        const float* __restrict__ ln2g, const float* __restrict__ ln2b,
        const int* __restrict__ tbl, float* __restrict__ out) {
    __shared__ __align__(16) short zb[16 * 72];
    __shared__ __align__(16) short hb[4][16 * 520];
    __shared__ float part[4 * 16 * 64];
    int tid = threadIdx.x;
    int row0 = blockIdx.x * 16;
    for (int i = tid; i < 1024; i += 256)
        zb[(i >> 6) * 72 + (i & 63)] = f2bf(z1[(long)row0 * 64 + i]);
    __syncthreads();
    int lane = tid & 63, wv = tid >> 6;
    int quad = lane >> 4, m16 = lane & 15;
    int mo[4], no[4];
#pragma unroll
    for (int r = 0; r < 4; r++) { mo[r] = tbl[lane * 4 + r]; no[r] = tbl[256 + lane * 4 + r]; }
    bf16x8 a0 = *(const bf16x8*)&zb[m16 * 72 + quad * 8];
    bf16x8 a1 = *(const bf16x8*)&zb[m16 * 72 + 32 + quad * 8];
    const short* pb1 = pw1 + (size_t)wv * 32 * 2 * 512;
    short* hbw = &hb[wv][0];
#pragma unroll 4
    for (int t = 0; t < 32; t++) {
        bf16x8 bA = *(const bf16x8*)(pb1 + ((t * 2 + 0) << 9) + (lane << 3));
        bf16x8 bB = *(const bf16x8*)(pb1 + ((t * 2 + 1) << 9) + (lane << 3));
        f32x4 acc = {0.f, 0.f, 0.f, 0.f};
        acc = __builtin_amdgcn_mfma_f32_16x16x32_bf16(a0, bA, acc, 0, 0, 0);
        acc = __builtin_amdgcn_mfma_f32_16x16x32_bf16(a1, bB, acc, 0, 0, 0);
#pragma unroll
        for (int r = 0; r < 4; r++) {
            float v = acc[r] + b1[wv * 512 + t * 16 + no[r]];
            v = v > 0.f ? v : 0.f;
            hbw[mo[r] * 520 + t * 16 + no[r]] = f2bf(v);
        }
    }
    __syncthreads();
    f32x4 acc2[4] = {{0.f,0.f,0.f,0.f},{0.f,0.f,0.f,0.f},{0.f,0.f,0.f,0.f},{0.f,0.f,0.f,0.f}};
    const short* pb2 = pw2 + (size_t)wv * 16 * 4 * 512;
#pragma unroll 2
    for (int kt = 0; kt < 16; kt++) {
        bf16x8 af = *(const bf16x8*)&hbw[m16 * 520 + kt * 32 + quad * 8];
#pragma unroll
        for (int nt = 0; nt < 4; nt++) {
            bf16x8 bfr = *(const bf16x8*)(pb2 + ((kt * 4 + nt) << 9) + (lane << 3));
            acc2[nt] = __builtin_amdgcn_mfma_f32_16x16x32_bf16(af, bfr, acc2[nt], 0, 0, 0);
        }
    }
#pragma unroll
    for (int nt = 0; nt < 4; nt++)
#pragma unroll
        for (int r = 0; r < 4; r++)
            part[wv * 1024 + mo[r] * 64 + nt * 16 + no[r]] = acc2[nt][r];
    __syncthreads();
    int col = tid & 63, rq = tid >> 6;
    float g = ln2g[col], bb = ln2b[col], bias2 = b2[col];
#pragma unroll
    for (int k2 = 0; k2 < 4; k2++) {
        int r = rq + k2 * 4;
        float val = part[r * 64 + col] + part[1024 + r * 64 + col]
                  + part[2048 + r * 64 + col] + part[3072 + r * 64 + col]
                  + z1[(long)(row0 + r) * 64 + col] + bias2;
        float sum = val, sq = val * val;
#pragma unroll
        for (int dlt = 32; dlt; dlt >>= 1) { sum += __shfl_xor(sum, dlt); sq += __shfl_xor(sq, dlt); }
        float mu = sum * (1.f / 64.f);
        float var = sq * (1.f / 64.f) - mu * mu;
        out[(long)(row0 + r) * 64 + col] = (val - mu) * rsqrtf(var + 1e-5f) * g + bb;
    }
}

extern "C" void kernel_launch(void* const* d_in, const int* in_sizes, int n_in,
                              void* d_out, int out_size, void* d_ws, size_t ws_size,
                              hipStream_t stream) {
    const float* x_seq      = (const float*)d_in[0];
    const int*   edge_index = (const int*)  d_in[1];
    const float* edge_weight= (const float*)d_in[2];
    const float* W_gat      = (const float*)d_in[3];
    const float* att_src    = (const float*)d_in[4];
    const float* att_dst    = (const float*)d_in[5];
    const float* W_edge     = (const float*)d_in[6];
    const float* att_edge   = (const float*)d_in[7];
    const float* gat_bias   = (const float*)d_in[8];
    const float* W_proj     = (const float*)d_in[9];
    const float* b_proj     = (const float*)d_in[10];
    const float* Wqkv       = (const float*)d_in[11];
    const float* bqkv       = (const float*)d_in[12];
    const float* Wo         = (const float*)d_in[13];
    const float* bo         = (const float*)d_in[14];
    const float* ln1g       = (const float*)d_in[15];
    const float* ln1b       = (const float*)d_in[16];
    const float* W1         = (const float*)d_in[17];
    const float* b1         = (const float*)d_in[18];
    const float* W2         = (const float*)d_in[19];
    const float* b2         = (const float*)d_in[20];
    const float* ln2g       = (const float*)d_in[21];
    const float* ln2b       = (const float*)d_in[22];
    float* outp = (float*)d_out;

    float* wsf = (float*)d_ws;
    float* h      = wsf + OFF_H;
    float* a_src  = wsf + OFF_ASRC;
    float* a_dst  = wsf + OFF_ADST;
    float* outg   = wsf + OFF_Y;
    float* Wfused = wsf + OFF_WF;
    float* bfv    = Wfused + 32 * 192;
    float* z1     = wsf + OFF_Z1;
    float* scal   = wsf + OFF_SCAL;
    int*   cnt    = (int*)(wsf + OFF_SCAL + 16);
    int*   rowptr = cnt + 2000;
    int*   csr_src= rowptr + 2001;
    float* csr_ew = (float*)(csr_src + 34000);
    short* pw1    = (short*)(wsf + OFF_PACK);
    short* pw2    = pw1 + 131072;
    int*   tbl    = (int*)(wsf + OFF_TBL);

    // one memset covers scal[16] + cnt[2000]
    hipMemsetAsync(scal, 0, (16 + NV) * sizeof(float), stream);
    mega_kernel<<<GH_BLOCKS + EH_BLOCKS + FU_BLOCKS + 2, 256, 0, stream>>>(
        x_seq, W_gat, att_src, att_dst, h, a_src, a_dst,
        edge_index, edge_weight, cnt, scal,
        W_proj, b_proj, Wqkv, bqkv, Wfused, bfv, W_edge, att_edge, tbl);
    scan_pack_kernel<<<1025, 256, 0, stream>>>(cnt, rowptr, cnt, W1, W2, pw1, pw2, tbl);
    scatter_kernel<<<(ETV + 255) / 256, 256, 0, stream>>>(edge_index, edge_weight, scal, cnt,
                                                          csr_src, csr_ew);
    gat_agg_kernel<<<GV * NV / 8, 256, 0, stream>>>(h, a_src, a_dst, rowptr, csr_src, csr_ew, scal,
                                                    gat_bias, outg);
    attn_kernel<<<BV * NV, 256, 0, stream>>>(outg, Wfused, bfv, W_proj, b_proj, Wo, bo, ln1g, ln1b, z1);
    ff_mfma_kernel<<<BV * NV / 16, 256, 0, stream>>>(z1, pw1, pw2, b1, b2, ln2g, ln2b, tbl, outp);
}